// Round 5
// baseline (1559.923 us; speedup 1.0000x reference)
//
#include <hip/hip_runtime.h>

#define NB 8
#define NT 512
#define NS 1024
#define NV 32000
#define BT 4096
#define SQH 0.70710678118654752440f
#define ATTN_SCALE 11.313708498984761f

typedef __attribute__((ext_vector_type(8))) short bf16x8;
typedef __attribute__((ext_vector_type(4))) float f32x4;
typedef unsigned short u16_t;
typedef unsigned int u32_t;

#define MFMA16(a, b, c) __builtin_amdgcn_mfma_f32_16x16x32_bf16((a), (b), (c), 0, 0, 0)

typedef __attribute__((address_space(1))) const u32_t gas_u32;
typedef __attribute__((address_space(3))) u32_t las_u32;
__device__ __forceinline__ void gld_lds16(const u16_t* g, u16_t* l){
  __builtin_amdgcn_global_load_lds((gas_u32*)g, (las_u32*)l, 16, 0, 0);
}

__device__ __forceinline__ u16_t f2bf(float f){
  union { float f; u32_t i; } v; v.f = f;
  return (u16_t)((v.i + 0x7fffu + ((v.i >> 16) & 1u)) >> 16);
}

struct Params {
  const float *input_x, *enc_out, *enc_att, *W1, *b1, *convW, *convb,
              *Wce, *bce, *Wec, *bec, *W2, *b2, *W3, *b3;
  u16_t *Wt, *W3t;
  float *dl1v, *yB;
  u16_t *ybf;
  float *part;
  u16_t *y2bf;
  float *esum;
  u16_t *eabf, *eoT;
  u32_t *bar;
  float *out;
};

struct AttnS {
  float yml[16][68];
  float pgS[16][68];
  u16_t pgb[16][72];
  float aof[4][64][17];
  float aosm[16][68];
  float reds[4][16];
  float invt[16];
};

// ---------- manual grid barrier (monotonic counter; init kernel zeroes it) ------
__device__ __forceinline__ void gridbar(u32_t* bar, u32_t target){
  __syncthreads();
  if(threadIdx.x == 0){
    __threadfence();                       // release: flush L1/L2 writes agent-wide
    atomicAdd(bar, 1u);                    // device-scope arrive
    while(__hip_atomic_load(bar, __ATOMIC_RELAXED, __HIP_MEMORY_SCOPE_AGENT) < target)
      __builtin_amdgcn_s_sleep(8);
    __threadfence();                       // acquire: invalidate stale L1
  }
  __syncthreads();
}

__global__ void k_init(u32_t* bar){
  if(threadIdx.x == 0) *bar = 0u;
}

// ================= P0: heterogeneous prep tasks =================
__device__ void p0_task(const Params& P, char* smem, int tid, int t){
  if(t < 320){
    // convW [5][64][ic][oc] -> swizzled bf16 image (kh,kw) 16KB each
    float (*tile)[130] = (float(*)[130])smem;
    const float* src = P.convW + (size_t)t * 8192;
    for(int i = tid; i < 8192; i += 256) tile[i >> 7][i & 127] = src[i];
    __syncthreads();
    u16_t* dst = P.Wt + (size_t)t * 8192;
    for(int i = tid; i < 8192; i += 256){
      int oc = i >> 6;
      int ic = (((i & 63) << 1) ^ ((oc & 7) << 4)) >> 1;
      dst[i] = f2bf(tile[ic][oc]);
    }
  } else if(t < 448){
    // ea -> bf16 [b][s][e]; eo -> bf16 transposed [b][e][s]
    int blk = t - 320;
    int b = blk >> 4, s0 = (blk & 15) << 6;
    float (*tile)[65] = (float(*)[65])smem;
    const float* easrc = P.enc_att + ((size_t)b * NS + s0) * 64;
    u16_t* eadst = P.eabf + ((size_t)b * NS + s0) * 64;
    for(int i = tid; i < 512; i += 256){
      float4 f0 = *(const float4*)(easrc + i * 8);
      float4 f1 = *(const float4*)(easrc + i * 8 + 4);
      union { u32_t u[4]; bf16x8 v; } pk;
      pk.u[0] = f2bf(f0.x) | ((u32_t)f2bf(f0.y) << 16);
      pk.u[1] = f2bf(f0.z) | ((u32_t)f2bf(f0.w) << 16);
      pk.u[2] = f2bf(f1.x) | ((u32_t)f2bf(f1.y) << 16);
      pk.u[3] = f2bf(f1.z) | ((u32_t)f2bf(f1.w) << 16);
      *(bf16x8*)(eadst + i * 8) = pk.v;
    }
    const float* eosrc = P.enc_out + ((size_t)b * NS + s0) * 64;
    for(int i = tid; i < 1024; i += 256){
      int s = i >> 4, e0 = (i & 15) * 4;
      float4 f = *(const float4*)(eosrc + s * 64 + e0);
      tile[s][e0] = f.x; tile[s][e0 + 1] = f.y; tile[s][e0 + 2] = f.z; tile[s][e0 + 3] = f.w;
    }
    __syncthreads();
    for(int i = tid; i < 512; i += 256){
      int e = i >> 3, sc = (i & 7) * 8;
      union { u32_t u[4]; bf16x8 v; } pk;
      #pragma unroll
      for(int j = 0; j < 4; j++){
        float lo = tile[sc + 2 * j][e], hi = tile[sc + 2 * j + 1][e];
        pk.u[j] = f2bf(lo) | ((u32_t)f2bf(hi) << 16);
      }
      *(bf16x8*)(P.eoT + ((size_t)b * 64 + e) * NS + s0 + sc) = pk.v;
    }
  } else if(t < 573){
    // W3 [e][v] -> W3t [v][e] bf16
    int v = (t - 448) * 256 + tid;
    u32_t pk[32];
    #pragma unroll
    for(int e = 0; e < 64; e += 2){
      u32_t lo = f2bf(P.W3[(size_t)e * NV + v]);
      u32_t hi = f2bf(P.W3[(size_t)(e + 1) * NV + v]);
      pk[e >> 1] = lo | (hi << 16);
    }
    u32_t* dst = (u32_t*)(P.W3t + (size_t)v * 64);
    #pragma unroll
    for(int i = 0; i < 32; i++) dst[i] = pk[i];
  } else if(t < 701){
    // zero ybf pad rows
    int i = (t - 573) * 256 + tid;
    int b = i >> 12, rem = i & 4095;
    int pr = rem >> 6, c = rem & 63;
    int row = pr < 31 ? pr : pr + 512;
    P.ybf[((size_t)b * 576 + row) * 64 + c] = 0;
  } else {
    // dl1 = relu(x@W1+b1) + padded bf16 image
    int r0 = (t - 701) * 4;
    float (*xs)[64] = (float(*)[64])smem;
    xs[tid >> 6][tid & 63] = P.input_x[(size_t)r0 * 64 + tid];
    __syncthreads();
    int h = tid & 63, rr = tid >> 6;
    float acc = P.b1[h];
    #pragma unroll 16
    for(int e = 0; e < 64; e++) acc = fmaf(xs[rr][e], P.W1[e * 64 + h], acc);
    float v = fmaxf(acc, 0.f);
    int row = r0 + rr;
    P.dl1v[(size_t)row * 64 + h] = v;
    P.ybf[((size_t)(row >> 9) * 576 + (row & 511) + 31) * 64 + h] = f2bf(v);
  }
  __syncthreads();
}

// ================= conv task (implicit GEMM, per-kh partial) =================
__device__ void conv_task(const Params& P, char* smem, int tid, int task){
  int vt = task >> 3, tt = task & 7;
  int kh, b;
  if(vt < 6)      { kh = 0; b = 2 + vt; }
  else if(vt < 13){ kh = 1; b = 1 + (vt - 6); }
  else if(vt < 21){ kh = 2; b = vt - 13; }
  else if(vt < 28){ kh = 3; b = vt - 21; }
  else            { kh = 4; b = vt - 28; }
  int t0 = tt << 6;
  int bp = b + kh - 2;

  u16_t* strip = (u16_t*)smem;                               // 127*72 u16
  u16_t (*wtile)[8192] = (u16_t(*)[8192])(smem + 18288);     // 2 x 16 KB

  int lane = tid & 63, wid = tid >> 6;
  int l15 = lane & 15, lgp = lane >> 4;

  const u16_t* ysrc = P.ybf + ((size_t)bp * 576 + t0) * 64;
  for(int li = tid; li < 1016; li += 256)
    *(bf16x8*)(strip + (li >> 3) * 72 + (li & 7) * 8) = *(const bf16x8*)(ysrc + li * 8);

  const u16_t* wsrc = P.Wt + (size_t)kh * 64 * 8192;
  {
    const u16_t* g = wsrc + tid * 8;
    #pragma unroll
    for(int j = 0; j < 4; j++)
      gld_lds16(g + j * 2048, &wtile[0][j * 2048 + wid * 512]);
  }
  __syncthreads();

  int wm = wid >> 1, wn = wid & 1;
  f32x4 acc[2][4];
  #pragma unroll
  for(int m = 0; m < 2; m++)
    #pragma unroll
    for(int n = 0; n < 4; n++) acc[m][n] = (f32x4){0.f, 0.f, 0.f, 0.f};
  int arow0 = wm * 32 + l15;

  int qoff[2][4];
  #pragma unroll
  for(int ks = 0; ks < 2; ks++)
    #pragma unroll
    for(int nf = 0; nf < 4; nf++){
      int oc = wn * 64 + nf * 16 + l15;
      int byte = (oc << 7) | (((ks << 6) | (lgp << 4)) ^ ((oc & 7) << 4));
      qoff[ks][nf] = byte >> 1;
    }

  for(int kw = 0; kw < 64; kw++){
    int cur = kw & 1;
    if(kw < 63){
      const u16_t* g = wsrc + (size_t)(kw + 1) * 8192 + tid * 8;
      #pragma unroll
      for(int j = 0; j < 4; j++)
        gld_lds16(g + j * 2048, &wtile[cur ^ 1][j * 2048 + wid * 512]);
      asm volatile("s_waitcnt vmcnt(4)" ::: "memory");
    } else {
      asm volatile("s_waitcnt vmcnt(0)" ::: "memory");
    }
    __builtin_amdgcn_s_barrier();
    const u16_t* wt = wtile[cur];
    #pragma unroll
    for(int ks = 0; ks < 2; ks++){
      bf16x8 a0 = *(const bf16x8*)(strip + (arow0 + kw) * 72 + ks * 32 + lgp * 8);
      bf16x8 a1 = *(const bf16x8*)(strip + (arow0 + 16 + kw) * 72 + ks * 32 + lgp * 8);
      bf16x8 q0 = *(const bf16x8*)(wt + qoff[ks][0]);
      bf16x8 q1 = *(const bf16x8*)(wt + qoff[ks][1]);
      bf16x8 q2 = *(const bf16x8*)(wt + qoff[ks][2]);
      bf16x8 q3 = *(const bf16x8*)(wt + qoff[ks][3]);
      acc[0][0] = MFMA16(a0, q0, acc[0][0]);
      acc[0][1] = MFMA16(a0, q1, acc[0][1]);
      acc[0][2] = MFMA16(a0, q2, acc[0][2]);
      acc[0][3] = MFMA16(a0, q3, acc[0][3]);
      acc[1][0] = MFMA16(a1, q0, acc[1][0]);
      acc[1][1] = MFMA16(a1, q1, acc[1][1]);
      acc[1][2] = MFMA16(a1, q2, acc[1][2]);
      acc[1][3] = MFMA16(a1, q3, acc[1][3]);
    }
    asm volatile("s_waitcnt lgkmcnt(0)" ::: "memory");
    __builtin_amdgcn_s_barrier();
  }

  float* dst = P.part + ((size_t)kh * BT + (size_t)b * 512 + t0) * 128;
  #pragma unroll
  for(int mf = 0; mf < 2; mf++)
    #pragma unroll
    for(int nf = 0; nf < 4; nf++)
      #pragma unroll
      for(int r = 0; r < 4; r++){
        int row = wm * 32 + mf * 16 + lgp * 4 + r;
        int col = wn * 64 + nf * 16 + l15;
        dst[row * 128 + col] = acc[mf][nf][r];
      }
  __syncthreads();
}

// ================= fused GLU + attention (+w2 tail on last layer) =================
__device__ void attn_task(const Params& P, char* smem, int tid, int task, int L,
                          const float* ycur){
  AttnS* S = (AttnS*)smem;
  int row0 = task << 4;
  int b = row0 >> 9;
  int lane = tid & 63, w = tid >> 6;
  int l15 = lane & 15, lgp = lane >> 4;

  // phase 0: GLU + residual
  for(int i = tid; i < 1024; i += 256){
    int r = i >> 6, h = i & 63;
    int grow = row0 + r;
    float ca = P.convb[h], cb = P.convb[64 + h];
    #pragma unroll
    for(int kh = 0; kh < 5; kh++){
      int bpp = b + kh - 2;
      if(bpp >= 0 && bpp < NB){
        const float* p = P.part + ((size_t)kh * BT + grow) * 128;
        ca += p[h]; cb += p[64 + h];
      }
    }
    float sig = 1.f / (1.f + __expf(-cb));
    S->yml[r][h] = (ca * sig + ycur[(size_t)grow * 64 + h]) * SQH;
  }
  __syncthreads();
  // phase 0b: pg logits
  {
    int h = tid & 63, g = tid >> 6;
    float a0 = P.bce[h], a1 = a0, a2 = a0, a3 = a0;
    #pragma unroll 16
    for(int e = 0; e < 64; e++){
      float wv = P.Wce[e * 64 + h];
      a0 = fmaf(S->yml[g * 4 + 0][e], wv, a0);
      a1 = fmaf(S->yml[g * 4 + 1][e], wv, a1);
      a2 = fmaf(S->yml[g * 4 + 2][e], wv, a2);
      a3 = fmaf(S->yml[g * 4 + 3][e], wv, a3);
    }
    S->pgS[g * 4 + 0][h] = a0; S->pgS[g * 4 + 1][h] = a1;
    S->pgS[g * 4 + 2][h] = a2; S->pgS[g * 4 + 3][h] = a3;
  }
  __syncthreads();
  // phase 1: softmax over 64 -> normalized bf16
  {
    int r = tid >> 5, j = tid & 31;
    #pragma unroll
    for(int rr = r; rr < 16; rr += 8){
      float v1 = __expf(S->pgS[rr][j]), v2 = __expf(S->pgS[rr][j + 32]);
      float s = v1 + v2;
      s += __shfl_xor(s, 1); s += __shfl_xor(s, 2); s += __shfl_xor(s, 4);
      s += __shfl_xor(s, 8); s += __shfl_xor(s, 16);
      float inv = 1.f / s;
      S->pgb[rr][j] = f2bf(v1 * inv); S->pgb[rr][j + 32] = f2bf(v2 * inv);
    }
  }
  __syncthreads();

  // phase 2: per-wave 256-s slice
  bf16x8 qpg0 = *(const bf16x8*)&S->pgb[l15][lgp * 8];
  bf16x8 qpg1 = *(const bf16x8*)&S->pgb[l15][32 + lgp * 8];
  float sumacc = 0.f;
  f32x4 ao[4];
  #pragma unroll
  for(int et = 0; et < 4; et++) ao[et] = (f32x4){0.f, 0.f, 0.f, 0.f};
  const u16_t* eab = P.eabf + ((size_t)b * NS + w * 256) * 64;
  const u16_t* eob = P.eoT + (size_t)b * 64 * NS + w * 256;
  for(int sc = 0; sc < 8; sc++){
    int sb = sc * 32;
    const u16_t* ar = eab + (size_t)(sb + l15) * 64 + lgp * 8;
    bf16x8 a00 = *(const bf16x8*)ar;
    bf16x8 a01 = *(const bf16x8*)(ar + 32);
    bf16x8 a10 = *(const bf16x8*)(ar + 1024);
    bf16x8 a11 = *(const bf16x8*)(ar + 1024 + 32);
    f32x4 s0 = {0.f, 0.f, 0.f, 0.f}, s1 = {0.f, 0.f, 0.f, 0.f};
    s0 = MFMA16(a00, qpg0, s0); s0 = MFMA16(a01, qpg1, s0);
    s1 = MFMA16(a10, qpg0, s1); s1 = MFMA16(a11, qpg1, s1);
    float p00 = __expf(s0[0]), p01 = __expf(s0[1]), p02 = __expf(s0[2]), p03 = __expf(s0[3]);
    float p10 = __expf(s1[0]), p11 = __expf(s1[1]), p12 = __expf(s1[2]), p13 = __expf(s1[3]);
    sumacc += (p00 + p01) + (p02 + p03) + (p10 + p11) + (p12 + p13);
    u32_t A0, B0, A1, B1;
    asm("v_cvt_pk_bf16_f32 %0, %1, %2" : "=v"(A0) : "v"(p00), "v"(p01));
    asm("v_cvt_pk_bf16_f32 %0, %1, %2" : "=v"(B0) : "v"(p02), "v"(p03));
    asm("v_cvt_pk_bf16_f32 %0, %1, %2" : "=v"(A1) : "v"(p10), "v"(p11));
    asm("v_cvt_pk_bf16_f32 %0, %1, %2" : "=v"(B1) : "v"(p12), "v"(p13));
    int src0 = l15 + ((lgp & 1) << 5);
    int src1 = src0 + 16;
    u32_t w0a = (u32_t)__shfl((int)A0, src0, 64), w0b = (u32_t)__shfl((int)A1, src0, 64);
    u32_t w1a = (u32_t)__shfl((int)B0, src0, 64), w1b = (u32_t)__shfl((int)B1, src0, 64);
    u32_t w2a = (u32_t)__shfl((int)A0, src1, 64), w2b = (u32_t)__shfl((int)A1, src1, 64);
    u32_t w3a = (u32_t)__shfl((int)B0, src1, 64), w3b = (u32_t)__shfl((int)B1, src1, 64);
    bool hi = lgp >= 2;
    union { u32_t u[4]; bf16x8 v; } bav;
    bav.u[0] = hi ? w0b : w0a; bav.u[1] = hi ? w1b : w1a;
    bav.u[2] = hi ? w2b : w2a; bav.u[3] = hi ? w3b : w3a;
    #pragma unroll
    for(int et = 0; et < 4; et++){
      const u16_t* er = eob + (size_t)(et * 16 + l15) * NS + sb + lgp * 8;
      bf16x8 ae = *(const bf16x8*)er;
      ao[et] = MFMA16(ae, bav.v, ao[et]);
    }
  }
  sumacc += __shfl_xor(sumacc, 16);
  sumacc += __shfl_xor(sumacc, 32);
  if(lane < 16) S->reds[w][l15] = sumacc;
  #pragma unroll
  for(int et = 0; et < 4; et++)
    #pragma unroll
    for(int r = 0; r < 4; r++)
      S->aof[w][et * 16 + lgp * 4 + r][l15] = ao[et][r];
  __syncthreads();
  if(tid < 16)
    S->invt[tid] = ATTN_SCALE / (S->reds[0][tid] + S->reds[1][tid] + S->reds[2][tid] + S->reds[3][tid]);
  __syncthreads();
  // phase 3: combine wave partials, transpose
  for(int i = tid; i < 1024; i += 256){
    int e = i >> 4, t = i & 15;
    S->aosm[t][e] = (S->aof[0][e][t] + S->aof[1][e][t] + S->aof[2][e][t] + S->aof[3][e][t]) * S->invt[t];
  }
  __syncthreads();
  // phase 4: y logits = aosm @ Wec + bec
  {
    int h = tid & 63, g = tid >> 6;
    float a0 = P.bec[h], a1 = a0, a2 = a0, a3 = a0;
    #pragma unroll 16
    for(int e = 0; e < 64; e++){
      float wv = P.Wec[e * 64 + h];
      a0 = fmaf(S->aosm[g * 4 + 0][e], wv, a0);
      a1 = fmaf(S->aosm[g * 4 + 1][e], wv, a1);
      a2 = fmaf(S->aosm[g * 4 + 2][e], wv, a2);
      a3 = fmaf(S->aosm[g * 4 + 3][e], wv, a3);
    }
    S->pgS[g * 4 + 0][h] = a0; S->pgS[g * 4 + 1][h] = a1;
    S->pgS[g * 4 + 2][h] = a2; S->pgS[g * 4 + 3][h] = a3;
  }
  __syncthreads();
  // phase 5: softmax over 64
  {
    int r = tid >> 5, j = tid & 31;
    #pragma unroll
    for(int rr = r; rr < 16; rr += 8){
      float v1 = __expf(S->pgS[rr][j]), v2 = __expf(S->pgS[rr][j + 32]);
      float s = v1 + v2;
      s += __shfl_xor(s, 1); s += __shfl_xor(s, 2); s += __shfl_xor(s, 4);
      s += __shfl_xor(s, 8); s += __shfl_xor(s, 16);
      float inv = 1.f / s;
      float o1 = v1 * inv, o2 = v2 * inv;
      if(L < 2){
        int grow = row0 + rr;
        P.yB[(size_t)grow * 64 + j] = o1;
        P.yB[(size_t)grow * 64 + j + 32] = o2;
        size_t yb = ((size_t)(grow >> 9) * 576 + (grow & 511) + 31) * 64;
        P.ybf[yb + j] = f2bf(o1);
        P.ybf[yb + j + 32] = f2bf(o2);
      } else {
        S->yml[rr][j] = o1;
        S->yml[rr][j + 32] = o2;
      }
    }
  }
  if(L == 2){
    __syncthreads();
    // w2 tail: x = (y + dl1)*SQ
    for(int i = tid; i < 1024; i += 256){
      int r = i >> 6, h = i & 63;
      S->pgS[r][h] = (S->yml[r][h] + P.dl1v[(size_t)(row0 + r) * 64 + h]) * SQH;
    }
    __syncthreads();
    int h = tid & 63, g = tid >> 6;
    float a0 = P.b2[h], a1 = a0, a2 = a0, a3 = a0;
    #pragma unroll 16
    for(int e = 0; e < 64; e++){
      float wv = P.W2[e * 64 + h];
      a0 = fmaf(S->pgS[g * 4 + 0][e], wv, a0);
      a1 = fmaf(S->pgS[g * 4 + 1][e], wv, a1);
      a2 = fmaf(S->pgS[g * 4 + 2][e], wv, a2);
      a3 = fmaf(S->pgS[g * 4 + 3][e], wv, a3);
    }
    P.y2bf[(size_t)(row0 + g * 4 + 0) * 64 + h] = f2bf(fmaxf(a0, 0.f));
    P.y2bf[(size_t)(row0 + g * 4 + 1) * 64 + h] = f2bf(fmaxf(a1, 0.f));
    P.y2bf[(size_t)(row0 + g * 4 + 2) * 64 + h] = f2bf(fmaxf(a2, 0.f));
    P.y2bf[(size_t)(row0 + g * 4 + 3) * 64 + h] = f2bf(fmaxf(a3, 0.f));
    if(tid < 16) P.esum[row0 + tid] = 0.f;
  }
  __syncthreads();
}

// ================= V-GEMM pass A =================
__device__ void va_task(const Params& P, int tid, int task){
  int m0 = (task & 63) << 6, ns = task >> 6;
  int lane = tid & 63, w = tid >> 6;
  int l15 = lane & 15, lgp = lane >> 4;
  bf16x8 a[4][2];
  #pragma unroll
  for(int mg = 0; mg < 4; mg++){
    const u16_t* ar = P.y2bf + ((size_t)(m0 + mg * 16 + l15) << 6) + lgp * 8;
    a[mg][0] = *(const bf16x8*)ar;
    a[mg][1] = *(const bf16x8*)(ar + 32);
  }
  float sums[4][4];
  #pragma unroll
  for(int mg = 0; mg < 4; mg++)
    #pragma unroll
    for(int r = 0; r < 4; r++) sums[mg][r] = 0.f;

  int nb0 = ns * 1600 + w * 400;
  for(int fi = 0; fi < 25; fi++){
    int n = nb0 + fi * 16 + l15;
    const u16_t* bp2 = P.W3t + ((size_t)n << 6) + lgp * 8;
    bf16x8 q0 = *(const bf16x8*)bp2;
    bf16x8 q1 = *(const bf16x8*)(bp2 + 32);
    float bias = P.b3[n];
    #pragma unroll
    for(int mg = 0; mg < 4; mg++){
      f32x4 acc = {0.f, 0.f, 0.f, 0.f};
      acc = MFMA16(a[mg][0], q0, acc);
      acc = MFMA16(a[mg][1], q1, acc);
      #pragma unroll
      for(int r = 0; r < 4; r++){
        float z = fmaxf(acc[r] + bias, 0.f);
        sums[mg][r] += __expf(z);
      }
    }
  }
  #pragma unroll
  for(int mg = 0; mg < 4; mg++)
    #pragma unroll
    for(int r = 0; r < 4; r++){
      float v = sums[mg][r];
      v += __shfl_xor(v, 1); v += __shfl_xor(v, 2);
      v += __shfl_xor(v, 4); v += __shfl_xor(v, 8);
      if(l15 == 0) atomicAdd(&P.esum[m0 + mg * 16 + lgp * 4 + r], v);
    }
}

// ================= V-GEMM pass B =================
__device__ void vb_task(const Params& P, char* smem, int tid, int task){
  int m0 = (task & 63) << 6, ns = task >> 6;
  int lane = tid & 63, w = tid >> 6;
  int l15 = lane & 15, lgp = lane >> 4;
  float (*obuf)[84] = (float(*)[84])smem;
  bf16x8 a[4][2];
  #pragma unroll
  for(int mg = 0; mg < 4; mg++){
    const u16_t* ar = P.y2bf + ((size_t)(m0 + mg * 16 + l15) << 6) + lgp * 8;
    a[mg][0] = *(const bf16x8*)ar;
    a[mg][1] = *(const bf16x8*)(ar + 32);
  }
  float invs[4][4];
  #pragma unroll
  for(int mg = 0; mg < 4; mg++)
    #pragma unroll
    for(int r = 0; r < 4; r++) invs[mg][r] = 1.f / P.esum[m0 + mg * 16 + lgp * 4 + r];

  int cb0 = ns * 1600;
  for(int si = 0; si < 25; si++){
    int cb = cb0 + si * 64;
    int n = cb + w * 16 + l15;
    const u16_t* bp2 = P.W3t + ((size_t)n << 6) + lgp * 8;
    bf16x8 q0 = *(const bf16x8*)bp2;
    bf16x8 q1 = *(const bf16x8*)(bp2 + 32);
    float bias = P.b3[n];
    #pragma unroll
    for(int mg = 0; mg < 4; mg++){
      f32x4 acc = {0.f, 0.f, 0.f, 0.f};
      acc = MFMA16(a[mg][0], q0, acc);
      acc = MFMA16(a[mg][1], q1, acc);
      #pragma unroll
      for(int r = 0; r < 4; r++){
        float z = fmaxf(acc[r] + bias, 0.f);
        obuf[mg * 16 + lgp * 4 + r][w * 16 + l15] = __expf(z) * invs[mg][r];
      }
    }
    __syncthreads();
    #pragma unroll
    for(int p = 0; p < 4; p++){
      int row = p * 16 + (tid >> 4);
      float4 v = *(const float4*)&obuf[row][(tid & 15) * 4];
      *(float4*)&P.out[(size_t)(m0 + row) * NV + cb + (tid & 15) * 4] = v;
    }
    __syncthreads();
  }
}

// ================= persistent mega kernel with manual grid barrier =================
__global__ __launch_bounds__(256, 1) void k_mega(Params P){
  __shared__ __align__(16) char smem[51072];
  int tid = threadIdx.x, bid = blockIdx.x;
  int nb = gridDim.x;
  u32_t ep = 0;

  for(int t = bid; t < 1725; t += nb) p0_task(P, smem, tid, t);
  gridbar(P.bar, ++ep * nb);

  const float* ycur = P.dl1v;
  for(int L = 0; L < 3; L++){
    for(int t = bid; t < 272; t += nb) conv_task(P, smem, tid, t);
    gridbar(P.bar, ++ep * nb);
    for(int t = bid; t < 256; t += nb) attn_task(P, smem, tid, t, L, ycur);
    gridbar(P.bar, ++ep * nb);
    ycur = P.yB;
  }

  {
    int s = (int)(((long)bid * 1280) / nb), e = (int)(((long)(bid + 1) * 1280) / nb);
    for(int t = s; t < e; t++) va_task(P, tid, t);
    gridbar(P.bar, ++ep * nb);
    for(int t = s; t < e; t++) vb_task(P, smem, tid, t);
  }
}

extern "C" void kernel_launch(void* const* d_in, const int* in_sizes, int n_in,
                              void* d_out, int out_size, void* d_ws, size_t ws_size,
                              hipStream_t stream){
  char* ws = (char*)d_ws;
  Params P;
  P.input_x = (const float*)d_in[0];
  P.enc_out = (const float*)d_in[1];
  P.enc_att = (const float*)d_in[2];
  P.W1    = (const float*)d_in[3];
  P.b1    = (const float*)d_in[4];
  P.convW = (const float*)d_in[5];
  P.convb = (const float*)d_in[6];
  P.Wce   = (const float*)d_in[7];
  P.bce   = (const float*)d_in[8];
  P.Wec   = (const float*)d_in[9];
  P.bec   = (const float*)d_in[10];
  P.W2    = (const float*)d_in[11];
  P.b2    = (const float*)d_in[12];
  P.W3    = (const float*)d_in[13];
  P.b3    = (const float*)d_in[14];

  P.Wt    = (u16_t*)(ws);                 // 5,242,880 B
  P.W3t   = (u16_t*)(ws + 5242880);       // 4,096,000 B
  P.dl1v  = (float*)(ws + 9338880);       // 1,048,576 B
  P.yB    = (float*)(ws + 11436032);      // 1,048,576 B
  P.ybf   = (u16_t*)(ws + 12484608);      //   589,824 B
  P.part  = (float*)(ws + 13074432);      // 10,485,760 B
  P.y2bf  = (u16_t*)(ws + 23560192);      //   524,288 B
  P.esum  = (float*)(ws + 24084480);      //    16,384 B
  P.eabf  = (u16_t*)(ws + 24100864);      // 1,048,576 B
  P.eoT   = (u16_t*)(ws + 25149440);      // 1,048,576 B
  P.bar   = (u32_t*)(ws + 26198016);      //         4 B
  P.out   = (float*)d_out;

  // safe co-residency: 1 block/CU by construction; verify via occupancy query
  int occ = 0;
  hipError_t oe = hipOccupancyMaxActiveBlocksPerMultiprocessor(&occ, k_mega, 256, 0);
  int nb = (oe == hipSuccess && occ >= 1) ? 256 : 64;

  k_init<<<dim3(1), dim3(64), 0, stream>>>(P.bar);
  k_mega<<<dim3(nb), dim3(256), 0, stream>>>(P);
}

// Round 7
// 440.483 us; speedup vs baseline: 3.5414x; 3.5414x over previous
//
#include <hip/hip_runtime.h>

#define NB 8
#define NT 512
#define NS 1024
#define NV 32000
#define BT 4096
#define SQH 0.70710678118654752440f
#define ATTN_SCALE 11.313708498984761f

typedef __attribute__((ext_vector_type(8))) short bf16x8;
typedef __attribute__((ext_vector_type(4))) float f32x4;
typedef unsigned short u16_t;
typedef unsigned int u32_t;

#define MFMA16(a, b, c) __builtin_amdgcn_mfma_f32_16x16x32_bf16((a), (b), (c), 0, 0, 0)

typedef __attribute__((address_space(1))) const u32_t gas_u32;
typedef __attribute__((address_space(3))) u32_t las_u32;
__device__ __forceinline__ void gld_lds16(const u16_t* g, u16_t* l){
  __builtin_amdgcn_global_load_lds((gas_u32*)g, (las_u32*)l, 16, 0, 0);
}

__device__ __forceinline__ u16_t f2bf(float f){
  union { float f; u32_t i; } v; v.f = f;
  return (u16_t)((v.i + 0x7fffu + ((v.i >> 16) & 1u)) >> 16);
}

// ================= merged prep kernel: 1725 heterogeneous block-tasks =============
// t in [0,320):   convW (kh,kw) slice -> swizzled bf16 image
// t in [320,448): ea -> bf16 [b][s][e]; eo -> bf16 transposed [b][e][s]
// t in [448,573): W3 [e][v] -> W3t [v][e] bf16 (coalesced via LDS transpose)
// t in [573,701): zero ybf pad rows
// t in [701,1725): dl1 = relu(x@W1+b1) (f32 out + padded bf16 image)
__global__ __launch_bounds__(256) void k_prep(
    const float* __restrict__ input_x, const float* __restrict__ enc_out,
    const float* __restrict__ enc_att, const float* __restrict__ W1,
    const float* __restrict__ b1, const float* __restrict__ convW,
    const float* __restrict__ W3,
    u16_t* __restrict__ Wt, u16_t* __restrict__ W3t, float* __restrict__ dl1v,
    u16_t* __restrict__ ybf, u16_t* __restrict__ eabf, u16_t* __restrict__ eoT){
  __shared__ __align__(16) char smem[33792];
  int tid = threadIdx.x, t = blockIdx.x;

  if(t < 320){
    float (*tile)[130] = (float(*)[130])smem;
    const float* src = convW + (size_t)t * 8192;
    for(int i = tid; i < 8192; i += 256) tile[i >> 7][i & 127] = src[i];
    __syncthreads();
    u16_t* dst = Wt + (size_t)t * 8192;
    for(int i = tid; i < 8192; i += 256){
      int oc = i >> 6;
      int ic = (((i & 63) << 1) ^ ((oc & 7) << 4)) >> 1;
      dst[i] = f2bf(tile[ic][oc]);
    }
  } else if(t < 448){
    int blk = t - 320;
    int b = blk >> 4, s0 = (blk & 15) << 6;
    float (*tile)[65] = (float(*)[65])smem;
    const float* easrc = enc_att + ((size_t)b * NS + s0) * 64;
    u16_t* eadst = eabf + ((size_t)b * NS + s0) * 64;
    for(int i = tid; i < 512; i += 256){
      float4 f0 = *(const float4*)(easrc + i * 8);
      float4 f1 = *(const float4*)(easrc + i * 8 + 4);
      union { u32_t u[4]; bf16x8 v; } pk;
      pk.u[0] = f2bf(f0.x) | ((u32_t)f2bf(f0.y) << 16);
      pk.u[1] = f2bf(f0.z) | ((u32_t)f2bf(f0.w) << 16);
      pk.u[2] = f2bf(f1.x) | ((u32_t)f2bf(f1.y) << 16);
      pk.u[3] = f2bf(f1.z) | ((u32_t)f2bf(f1.w) << 16);
      *(bf16x8*)(eadst + i * 8) = pk.v;
    }
    const float* eosrc = enc_out + ((size_t)b * NS + s0) * 64;
    for(int i = tid; i < 1024; i += 256){
      int s = i >> 4, e0 = (i & 15) * 4;
      float4 f = *(const float4*)(eosrc + s * 64 + e0);
      tile[s][e0] = f.x; tile[s][e0 + 1] = f.y; tile[s][e0 + 2] = f.z; tile[s][e0 + 3] = f.w;
    }
    __syncthreads();
    for(int i = tid; i < 512; i += 256){
      int e = i >> 3, sc = (i & 7) * 8;
      union { u32_t u[4]; bf16x8 v; } pk;
      #pragma unroll
      for(int j = 0; j < 4; j++){
        float lo = tile[sc + 2 * j][e], hi = tile[sc + 2 * j + 1][e];
        pk.u[j] = f2bf(lo) | ((u32_t)f2bf(hi) << 16);
      }
      *(bf16x8*)(eoT + ((size_t)b * 64 + e) * NS + s0 + sc) = pk.v;
    }
  } else if(t < 573){
    // coalesced W3 transpose: 256 v-columns per block
    u32_t (*lt)[33] = (u32_t(*)[33])smem;
    int v0 = (t - 448) * 256;
    for(int it = 0; it < 8; it++){
      int u = it * 256 + tid;        // 0..2047
      int rp = u >> 6;               // row-pair 0..31
      int c4 = (u & 63) * 4;
      const float* r0p = W3 + (size_t)(2 * rp) * NV + v0 + c4;
      float4 a4 = *(const float4*)r0p;
      float4 b4 = *(const float4*)(r0p + NV);
      lt[c4 + 0][rp] = f2bf(a4.x) | ((u32_t)f2bf(b4.x) << 16);
      lt[c4 + 1][rp] = f2bf(a4.y) | ((u32_t)f2bf(b4.y) << 16);
      lt[c4 + 2][rp] = f2bf(a4.z) | ((u32_t)f2bf(b4.z) << 16);
      lt[c4 + 3][rp] = f2bf(a4.w) | ((u32_t)f2bf(b4.w) << 16);
    }
    __syncthreads();
    u32_t* dst = (u32_t*)(W3t + (size_t)v0 * 64);
    for(int it = 0; it < 32; it++){
      int idx = it * 256 + tid;      // 0..8191
      dst[idx] = lt[idx >> 5][idx & 31];
    }
  } else if(t < 701){
    int i = (t - 573) * 256 + tid;
    int b = i >> 12, rem = i & 4095;
    int pr = rem >> 6, c = rem & 63;
    int row = pr < 31 ? pr : pr + 512;
    ybf[((size_t)b * 576 + row) * 64 + c] = 0;
  } else {
    int r0 = (t - 701) * 4;
    float (*xs)[64] = (float(*)[64])smem;
    xs[tid >> 6][tid & 63] = input_x[(size_t)r0 * 64 + tid];
    __syncthreads();
    int h = tid & 63, rr = tid >> 6;
    float acc = b1[h];
    #pragma unroll 16
    for(int e = 0; e < 64; e++) acc = fmaf(xs[rr][e], W1[e * 64 + h], acc);
    float v = fmaxf(acc, 0.f);
    int row = r0 + rr;
    dl1v[(size_t)row * 64 + h] = v;
    ybf[((size_t)(row >> 9) * 576 + (row & 511) + 31) * 64 + h] = f2bf(v);
  }
}

// ================= conv: implicit GEMM, 3-buffer depth-2 vmcnt pipeline ===========
__global__ __launch_bounds__(256) void k_conv(const u16_t* __restrict__ ybf,
                                              const u16_t* __restrict__ Wt,
                                              float* __restrict__ part){
  int mt = blockIdx.x;       // 0..63
  int kh = blockIdx.y;       // 0..4
  int b = mt >> 3, t0 = (mt & 7) << 6;
  int bp = b + kh - 2;
  if(bp < 0 || bp >= NB) return;
  __shared__ u16_t strip[127 * 64];        // granule-XOR-swizzled, no pad
  __shared__ u16_t wtile[3][8192];
  int tid = threadIdx.x;
  int lane = tid & 63, wid = tid >> 6;
  int l15 = lane & 15, lgp = lane >> 4;

  // strip staging: granule g of row r stored at granule (g ^ (r&7))
  const u16_t* ysrc = ybf + ((size_t)bp * 576 + t0) * 64;
  for(int li = tid; li < 1016; li += 256){
    int r = li >> 3, g = li & 7;
    *(bf16x8*)(strip + r * 64 + ((g ^ (r & 7)) << 3)) = *(const bf16x8*)(ysrc + li * 8);
  }

  const u16_t* wsrc = Wt + (size_t)kh * 64 * 8192;
  auto issue = [&](int kw){
    const u16_t* g = wsrc + (size_t)kw * 8192 + tid * 8;
    u16_t* l = &wtile[kw % 3][wid * 512];
    #pragma unroll
    for(int j = 0; j < 4; j++) gld_lds16(g + j * 2048, l + j * 2048);
  };
  issue(0); issue(1);
  __syncthreads();   // one-time full drain (strip + buf0/buf1)

  int wm = wid >> 1, wn = wid & 1;
  f32x4 acc[2][4];
  #pragma unroll
  for(int m = 0; m < 2; m++)
    #pragma unroll
    for(int n = 0; n < 4; n++) acc[m][n] = (f32x4){0.f, 0.f, 0.f, 0.f};
  int arow0 = wm * 32 + l15;

  int qoff[2][4];
  #pragma unroll
  for(int ks = 0; ks < 2; ks++)
    #pragma unroll
    for(int nf = 0; nf < 4; nf++){
      int oc = wn * 64 + nf * 16 + l15;
      int byte = (oc << 7) | (((ks << 6) | (lgp << 4)) ^ ((oc & 7) << 4));
      qoff[ks][nf] = byte >> 1;
    }

  for(int kw = 0; kw < 64; kw++){
    if(kw <= 61){
      issue(kw + 2);
      asm volatile("s_waitcnt vmcnt(8)" ::: "memory");   // kw's 4 loads retired
    } else if(kw == 62){
      asm volatile("s_waitcnt vmcnt(4)" ::: "memory");
    } else {
      asm volatile("s_waitcnt vmcnt(0)" ::: "memory");
    }
    __builtin_amdgcn_s_barrier();
    const u16_t* wt = wtile[kw % 3];
    int ra = arow0 + kw;
    int sw = (ra & 7);
    #pragma unroll
    for(int ks = 0; ks < 2; ks++){
      int g = (ks << 2) | lgp;
      bf16x8 a0 = *(const bf16x8*)(strip + ra * 64 + ((g ^ sw) << 3));
      bf16x8 a1 = *(const bf16x8*)(strip + (ra + 16) * 64 + ((g ^ ((ra + 16) & 7)) << 3));
      bf16x8 q0 = *(const bf16x8*)(wt + qoff[ks][0]);
      bf16x8 q1 = *(const bf16x8*)(wt + qoff[ks][1]);
      bf16x8 q2 = *(const bf16x8*)(wt + qoff[ks][2]);
      bf16x8 q3 = *(const bf16x8*)(wt + qoff[ks][3]);
      acc[0][0] = MFMA16(a0, q0, acc[0][0]);
      acc[0][1] = MFMA16(a0, q1, acc[0][1]);
      acc[0][2] = MFMA16(a0, q2, acc[0][2]);
      acc[0][3] = MFMA16(a0, q3, acc[0][3]);
      acc[1][0] = MFMA16(a1, q0, acc[1][0]);
      acc[1][1] = MFMA16(a1, q1, acc[1][1]);
      acc[1][2] = MFMA16(a1, q2, acc[1][2]);
      acc[1][3] = MFMA16(a1, q3, acc[1][3]);
    }
    asm volatile("s_waitcnt lgkmcnt(0)" ::: "memory");   // reads of buf[(kw+2)%3] done
    __builtin_amdgcn_s_barrier();                        // before iteration kw+2's overwrite
  }

  float* dst = part + ((size_t)kh * BT + (size_t)mt * 64) * 128;
  #pragma unroll
  for(int mf = 0; mf < 2; mf++)
    #pragma unroll
    for(int nf = 0; nf < 4; nf++)
      #pragma unroll
      for(int r = 0; r < 4; r++){
        int row = wm * 32 + mf * 16 + lgp * 4 + r;
        int col = wn * 64 + nf * 16 + l15;
        dst[row * 128 + col] = acc[mf][nf][r];
      }
}

// ================= fused GLU + attention (+w2 tail on last layer) =================
__global__ __launch_bounds__(256) void k_attn(const float* __restrict__ part,
    const float* __restrict__ convb, const float* __restrict__ ycur,
    const u16_t* __restrict__ eabf, const u16_t* __restrict__ eoT,
    const float* __restrict__ Wce, const float* __restrict__ bce,
    const float* __restrict__ Wec, const float* __restrict__ bec,
    float* __restrict__ ynext, u16_t* __restrict__ ybf,
    const float* __restrict__ dl1v, const float* __restrict__ W2,
    const float* __restrict__ b2, u16_t* __restrict__ y2bf,
    float* __restrict__ esum, int L){
  int row0 = blockIdx.x << 4;
  int b = row0 >> 9;
  int tid = threadIdx.x;
  int lane = tid & 63, w = tid >> 6;
  int l15 = lane & 15, lgp = lane >> 4;

  __shared__ float yml[16][68];
  __shared__ float pgS[16][68];
  __shared__ u16_t pgb[16][72];
  __shared__ float aof[4][64][17];
  __shared__ float aosm[16][68];
  __shared__ float reds[4][16];
  __shared__ float invt[16];

  // phase 0: GLU + residual
  for(int i = tid; i < 1024; i += 256){
    int r = i >> 6, h = i & 63;
    int grow = row0 + r;
    float ca = convb[h], cb = convb[64 + h];
    #pragma unroll
    for(int kh = 0; kh < 5; kh++){
      int bpp = b + kh - 2;
      if(bpp >= 0 && bpp < NB){
        const float* p = part + ((size_t)kh * BT + grow) * 128;
        ca += p[h]; cb += p[64 + h];
      }
    }
    float sig = 1.f / (1.f + __expf(-cb));
    yml[r][h] = (ca * sig + ycur[(size_t)grow * 64 + h]) * SQH;
  }
  __syncthreads();
  // phase 0b: pg logits
  {
    int h = tid & 63, g = tid >> 6;
    float a0 = bce[h], a1 = a0, a2 = a0, a3 = a0;
    #pragma unroll 16
    for(int e = 0; e < 64; e++){
      float wv = Wce[e * 64 + h];
      a0 = fmaf(yml[g * 4 + 0][e], wv, a0);
      a1 = fmaf(yml[g * 4 + 1][e], wv, a1);
      a2 = fmaf(yml[g * 4 + 2][e], wv, a2);
      a3 = fmaf(yml[g * 4 + 3][e], wv, a3);
    }
    pgS[g * 4 + 0][h] = a0; pgS[g * 4 + 1][h] = a1;
    pgS[g * 4 + 2][h] = a2; pgS[g * 4 + 3][h] = a3;
  }
  __syncthreads();
  // phase 1: softmax over 64 -> normalized bf16
  {
    int r = tid >> 5, j = tid & 31;
    #pragma unroll
    for(int rr = r; rr < 16; rr += 8){
      float v1 = __expf(pgS[rr][j]), v2 = __expf(pgS[rr][j + 32]);
      float s = v1 + v2;
      s += __shfl_xor(s, 1); s += __shfl_xor(s, 2); s += __shfl_xor(s, 4);
      s += __shfl_xor(s, 8); s += __shfl_xor(s, 16);
      float inv = 1.f / s;
      pgb[rr][j] = f2bf(v1 * inv); pgb[rr][j + 32] = f2bf(v2 * inv);
    }
  }
  __syncthreads();

  // phase 2: per-wave 256-s slice: S^T = mfma(ea, pg); P = exp; AV = mfma(eoT, P^T)
  bf16x8 qpg0 = *(const bf16x8*)&pgb[l15][lgp * 8];
  bf16x8 qpg1 = *(const bf16x8*)&pgb[l15][32 + lgp * 8];
  float sumacc = 0.f;
  f32x4 ao[4];
  #pragma unroll
  for(int et = 0; et < 4; et++) ao[et] = (f32x4){0.f, 0.f, 0.f, 0.f};
  const u16_t* eab = eabf + ((size_t)b * NS + w * 256) * 64;
  const u16_t* eob = eoT + (size_t)b * 64 * NS + w * 256;
  for(int sc = 0; sc < 8; sc++){
    int sb = sc * 32;
    const u16_t* ar = eab + (size_t)(sb + l15) * 64 + lgp * 8;
    bf16x8 a00 = *(const bf16x8*)ar;
    bf16x8 a01 = *(const bf16x8*)(ar + 32);
    bf16x8 a10 = *(const bf16x8*)(ar + 1024);
    bf16x8 a11 = *(const bf16x8*)(ar + 1024 + 32);
    f32x4 s0 = {0.f, 0.f, 0.f, 0.f}, s1 = {0.f, 0.f, 0.f, 0.f};
    s0 = MFMA16(a00, qpg0, s0); s0 = MFMA16(a01, qpg1, s0);
    s1 = MFMA16(a10, qpg0, s1); s1 = MFMA16(a11, qpg1, s1);
    float p00 = __expf(s0[0]), p01 = __expf(s0[1]), p02 = __expf(s0[2]), p03 = __expf(s0[3]);
    float p10 = __expf(s1[0]), p11 = __expf(s1[1]), p12 = __expf(s1[2]), p13 = __expf(s1[3]);
    sumacc += (p00 + p01) + (p02 + p03) + (p10 + p11) + (p12 + p13);
    u32_t A0, B0, A1, B1;
    asm("v_cvt_pk_bf16_f32 %0, %1, %2" : "=v"(A0) : "v"(p00), "v"(p01));
    asm("v_cvt_pk_bf16_f32 %0, %1, %2" : "=v"(B0) : "v"(p02), "v"(p03));
    asm("v_cvt_pk_bf16_f32 %0, %1, %2" : "=v"(A1) : "v"(p10), "v"(p11));
    asm("v_cvt_pk_bf16_f32 %0, %1, %2" : "=v"(B1) : "v"(p12), "v"(p13));
    int src0 = l15 + ((lgp & 1) << 5);
    int src1 = src0 + 16;
    u32_t w0a = (u32_t)__shfl((int)A0, src0, 64), w0b = (u32_t)__shfl((int)A1, src0, 64);
    u32_t w1a = (u32_t)__shfl((int)B0, src0, 64), w1b = (u32_t)__shfl((int)B1, src0, 64);
    u32_t w2a = (u32_t)__shfl((int)A0, src1, 64), w2b = (u32_t)__shfl((int)A1, src1, 64);
    u32_t w3a = (u32_t)__shfl((int)B0, src1, 64), w3b = (u32_t)__shfl((int)B1, src1, 64);
    bool hi = lgp >= 2;
    union { u32_t u[4]; bf16x8 v; } bav;
    bav.u[0] = hi ? w0b : w0a; bav.u[1] = hi ? w1b : w1a;
    bav.u[2] = hi ? w2b : w2a; bav.u[3] = hi ? w3b : w3a;
    #pragma unroll
    for(int et = 0; et < 4; et++){
      const u16_t* er = eob + (size_t)(et * 16 + l15) * NS + sb + lgp * 8;
      bf16x8 ae = *(const bf16x8*)er;
      ao[et] = MFMA16(ae, bav.v, ao[et]);
    }
  }
  sumacc += __shfl_xor(sumacc, 16);
  sumacc += __shfl_xor(sumacc, 32);
  if(lane < 16) reds[w][l15] = sumacc;
  #pragma unroll
  for(int et = 0; et < 4; et++)
    #pragma unroll
    for(int r = 0; r < 4; r++)
      aof[w][et * 16 + lgp * 4 + r][l15] = ao[et][r];
  __syncthreads();
  if(tid < 16)
    invt[tid] = ATTN_SCALE / (reds[0][tid] + reds[1][tid] + reds[2][tid] + reds[3][tid]);
  __syncthreads();
  // phase 3: combine wave partials, transpose
  for(int i = tid; i < 1024; i += 256){
    int e = i >> 4, t = i & 15;
    aosm[t][e] = (aof[0][e][t] + aof[1][e][t] + aof[2][e][t] + aof[3][e][t]) * invt[t];
  }
  __syncthreads();
  // phase 4: y logits = aosm @ Wec + bec
  {
    int h = tid & 63, g = tid >> 6;
    float a0 = bec[h], a1 = a0, a2 = a0, a3 = a0;
    #pragma unroll 16
    for(int e = 0; e < 64; e++){
      float wv = Wec[e * 64 + h];
      a0 = fmaf(aosm[g * 4 + 0][e], wv, a0);
      a1 = fmaf(aosm[g * 4 + 1][e], wv, a1);
      a2 = fmaf(aosm[g * 4 + 2][e], wv, a2);
      a3 = fmaf(aosm[g * 4 + 3][e], wv, a3);
    }
    pgS[g * 4 + 0][h] = a0; pgS[g * 4 + 1][h] = a1;
    pgS[g * 4 + 2][h] = a2; pgS[g * 4 + 3][h] = a3;
  }
  __syncthreads();
  // phase 5: softmax over 64
  {
    int r = tid >> 5, j = tid & 31;
    #pragma unroll
    for(int rr = r; rr < 16; rr += 8){
      float v1 = __expf(pgS[rr][j]), v2 = __expf(pgS[rr][j + 32]);
      float s = v1 + v2;
      s += __shfl_xor(s, 1); s += __shfl_xor(s, 2); s += __shfl_xor(s, 4);
      s += __shfl_xor(s, 8); s += __shfl_xor(s, 16);
      float inv = 1.f / s;
      float o1 = v1 * inv, o2 = v2 * inv;
      if(L < 2){
        int grow = row0 + rr;
        ynext[(size_t)grow * 64 + j] = o1;
        ynext[(size_t)grow * 64 + j + 32] = o2;
        size_t yb = ((size_t)(grow >> 9) * 576 + (grow & 511) + 31) * 64;
        ybf[yb + j] = f2bf(o1);
        ybf[yb + j + 32] = f2bf(o2);
      } else {
        yml[rr][j] = o1;
        yml[rr][j + 32] = o2;
      }
    }
  }
  if(L == 2){
    __syncthreads();
    for(int i = tid; i < 1024; i += 256){
      int r = i >> 6, h = i & 63;
      pgS[r][h] = (yml[r][h] + dl1v[(size_t)(row0 + r) * 64 + h]) * SQH;
    }
    __syncthreads();
    int h = tid & 63, g = tid >> 6;
    float a0 = b2[h], a1 = a0, a2 = a0, a3 = a0;
    #pragma unroll 16
    for(int e = 0; e < 64; e++){
      float wv = W2[e * 64 + h];
      a0 = fmaf(pgS[g * 4 + 0][e], wv, a0);
      a1 = fmaf(pgS[g * 4 + 1][e], wv, a1);
      a2 = fmaf(pgS[g * 4 + 2][e], wv, a2);
      a3 = fmaf(pgS[g * 4 + 3][e], wv, a3);
    }
    y2bf[(size_t)(row0 + g * 4 + 0) * 64 + h] = f2bf(fmaxf(a0, 0.f));
    y2bf[(size_t)(row0 + g * 4 + 1) * 64 + h] = f2bf(fmaxf(a1, 0.f));
    y2bf[(size_t)(row0 + g * 4 + 2) * 64 + h] = f2bf(fmaxf(a2, 0.f));
    y2bf[(size_t)(row0 + g * 4 + 3) * 64 + h] = f2bf(fmaxf(a3, 0.f));
    if(tid < 16) esum[row0 + tid] = 0.f;
  }
}

// ================= V-GEMM pass A =================
__global__ __launch_bounds__(256) void k_va(const u16_t* __restrict__ y2bf,
    const u16_t* __restrict__ W3t, const float* __restrict__ b3, float* __restrict__ esum){
  int m0 = blockIdx.x << 6, ns = blockIdx.y;
  int tid = threadIdx.x, lane = tid & 63, w = tid >> 6;
  int l15 = lane & 15, lgp = lane >> 4;
  bf16x8 a[4][2];
  #pragma unroll
  for(int mg = 0; mg < 4; mg++){
    const u16_t* ar = y2bf + ((size_t)(m0 + mg * 16 + l15) << 6) + lgp * 8;
    a[mg][0] = *(const bf16x8*)ar;
    a[mg][1] = *(const bf16x8*)(ar + 32);
  }
  float sums[4][4];
  #pragma unroll
  for(int mg = 0; mg < 4; mg++)
    #pragma unroll
    for(int r = 0; r < 4; r++) sums[mg][r] = 0.f;

  int nb0 = ns * 1600 + w * 400;
  for(int fi = 0; fi < 25; fi++){
    int n = nb0 + fi * 16 + l15;
    const u16_t* bp2 = W3t + ((size_t)n << 6) + lgp * 8;
    bf16x8 q0 = *(const bf16x8*)bp2;
    bf16x8 q1 = *(const bf16x8*)(bp2 + 32);
    float bias = b3[n];
    #pragma unroll
    for(int mg = 0; mg < 4; mg++){
      f32x4 acc = {0.f, 0.f, 0.f, 0.f};
      acc = MFMA16(a[mg][0], q0, acc);
      acc = MFMA16(a[mg][1], q1, acc);
      #pragma unroll
      for(int r = 0; r < 4; r++){
        float z = fmaxf(acc[r] + bias, 0.f);
        sums[mg][r] += __expf(z);
      }
    }
  }
  #pragma unroll
  for(int mg = 0; mg < 4; mg++)
    #pragma unroll
    for(int r = 0; r < 4; r++){
      float v = sums[mg][r];
      v += __shfl_xor(v, 1); v += __shfl_xor(v, 2);
      v += __shfl_xor(v, 4); v += __shfl_xor(v, 8);
      if(l15 == 0) atomicAdd(&esum[m0 + mg * 16 + lgp * 4 + r], v);
    }
}

// ================= V-GEMM pass B =================
__global__ __launch_bounds__(256) void k_vb(const u16_t* __restrict__ y2bf,
    const u16_t* __restrict__ W3t, const float* __restrict__ b3,
    const float* __restrict__ esum, float* __restrict__ out){
  int m0 = blockIdx.x << 6, ns = blockIdx.y;
  int tid = threadIdx.x, lane = tid & 63, w = tid >> 6;
  int l15 = lane & 15, lgp = lane >> 4;
  __shared__ float obuf[64][84];
  bf16x8 a[4][2];
  #pragma unroll
  for(int mg = 0; mg < 4; mg++){
    const u16_t* ar = y2bf + ((size_t)(m0 + mg * 16 + l15) << 6) + lgp * 8;
    a[mg][0] = *(const bf16x8*)ar;
    a[mg][1] = *(const bf16x8*)(ar + 32);
  }
  float invs[4][4];
  #pragma unroll
  for(int mg = 0; mg < 4; mg++)
    #pragma unroll
    for(int r = 0; r < 4; r++) invs[mg][r] = 1.f / esum[m0 + mg * 16 + lgp * 4 + r];

  int cb0 = ns * 1600;
  for(int si = 0; si < 25; si++){
    int cb = cb0 + si * 64;
    int n = cb + w * 16 + l15;
    const u16_t* bp2 = W3t + ((size_t)n << 6) + lgp * 8;
    bf16x8 q0 = *(const bf16x8*)bp2;
    bf16x8 q1 = *(const bf16x8*)(bp2 + 32);
    float bias = b3[n];
    #pragma unroll
    for(int mg = 0; mg < 4; mg++){
      f32x4 acc = {0.f, 0.f, 0.f, 0.f};
      acc = MFMA16(a[mg][0], q0, acc);
      acc = MFMA16(a[mg][1], q1, acc);
      #pragma unroll
      for(int r = 0; r < 4; r++){
        float z = fmaxf(acc[r] + bias, 0.f);
        obuf[mg * 16 + lgp * 4 + r][w * 16 + l15] = __expf(z) * invs[mg][r];
      }
    }
    __syncthreads();
    #pragma unroll
    for(int p = 0; p < 4; p++){
      int row = p * 16 + (tid >> 4);
      f32x4 v = *(const f32x4*)&obuf[row][(tid & 15) * 4];
      __builtin_nontemporal_store(v, (f32x4*)&out[(size_t)(m0 + row) * NV + cb + (tid & 15) * 4]);
    }
    __syncthreads();
  }
}

extern "C" void kernel_launch(void* const* d_in, const int* in_sizes, int n_in,
                              void* d_out, int out_size, void* d_ws, size_t ws_size,
                              hipStream_t stream){
  const float* input_x = (const float*)d_in[0];
  const float* enc_out = (const float*)d_in[1];
  const float* enc_att = (const float*)d_in[2];
  const float* W1    = (const float*)d_in[3];
  const float* b1    = (const float*)d_in[4];
  const float* convW = (const float*)d_in[5];
  const float* convb = (const float*)d_in[6];
  const float* Wce   = (const float*)d_in[7];
  const float* bce   = (const float*)d_in[8];
  const float* Wec   = (const float*)d_in[9];
  const float* bec   = (const float*)d_in[10];
  const float* W2    = (const float*)d_in[11];
  const float* b2    = (const float*)d_in[12];
  const float* W3    = (const float*)d_in[13];
  const float* b3    = (const float*)d_in[14];

  char* ws = (char*)d_ws;
  u16_t* Wt    = (u16_t*)(ws);                 // 5,242,880 B
  u16_t* W3t   = (u16_t*)(ws + 5242880);       // 4,096,000 B
  float* dl1v  = (float*)(ws + 9338880);       // 1,048,576 B
  float* yB    = (float*)(ws + 11436032);      // 1,048,576 B
  u16_t* ybf   = (u16_t*)(ws + 12484608);      //   589,824 B
  float* part  = (float*)(ws + 13074432);      // 10,485,760 B
  u16_t* y2bf  = (u16_t*)(ws + 23560192);      //   524,288 B
  float* esum  = (float*)(ws + 24084480);      //    16,384 B
  u16_t* eabf  = (u16_t*)(ws + 24100864);      // 1,048,576 B
  u16_t* eoT   = (u16_t*)(ws + 25149440);      // 1,048,576 B
  float* outp  = (float*)d_out;

  k_prep<<<dim3(1725), dim3(256), 0, stream>>>(input_x, enc_out, enc_att, W1, b1,
                                               convW, W3, Wt, W3t, dl1v, ybf, eabf, eoT);

  const float* ycur = dl1v;
  for(int it = 0; it < 3; it++){
    k_conv<<<dim3(64, 5), dim3(256), 0, stream>>>(ybf, Wt, part);
    k_attn<<<dim3(256), dim3(256), 0, stream>>>(part, convb, ycur, eabf, eoT,
                                                Wce, bce, Wec, bec, yB, ybf,
                                                dl1v, W2, b2, y2bf, esum, it);
    ycur = yB;
  }

  k_va<<<dim3(64, 20), dim3(256), 0, stream>>>(y2bf, W3t, b3, esum);
  k_vb<<<dim3(64, 20), dim3(256), 0, stream>>>(y2bf, W3t, b3, esum, outp);
}